// Round 1
// baseline (6813.550 us; speedup 1.0000x reference)
//
#include <hip/hip_runtime.h>
#include <hip/hip_bf16.h>
#include <math.h>

#define DIMC 3072
#define NHEADS 24
#define HD 128
#define SEQ 2560
#define TXTLEN 512
#define IMGLEN 2048

// ---------------------------------------------------------------------------
// GEMM: C[m][n] = sum_k A[m][k] * W[n][k]   (A row-major MxK, W row-major NxK)
// M = 2560 split at row 512: rows < 512 use A0/W0/C0, rows >= 512 use A1/W1/C1
// ---------------------------------------------------------------------------
constexpr int BM = 128, BN = 128, BK = 16;
constexpr int LDS_STRIDE = BK + 4; // 20 floats = 80B rows; 2-way bank alias only

__global__ __launch_bounds__(256)
void gemm_bt_kernel(const float* __restrict__ A0, const float* __restrict__ A1,
                    const float* __restrict__ W0, const float* __restrict__ W1,
                    float* __restrict__ C0, float* __restrict__ C1)
{
    __shared__ float As[BM][LDS_STRIDE];
    __shared__ float Ws[BN][LDS_STRIDE];

    const int bm = blockIdx.x, bn = blockIdx.y;
    const float* A; const float* W; float* C;
    int rowbase;
    if (bm < TXTLEN / BM) { A = A0; W = W0; C = C0; rowbase = bm * BM; }
    else                  { A = A1; W = W1; C = C1; rowbase = bm * BM - TXTLEN; }
    const int colbase = bn * BN;

    const int t  = threadIdx.x;
    const int tx = t & 15, ty = t >> 4;

    float acc[8][8];
#pragma unroll
    for (int i = 0; i < 8; ++i)
#pragma unroll
        for (int j = 0; j < 8; ++j) acc[i][j] = 0.f;

    for (int k0 = 0; k0 < DIMC; k0 += BK) {
        // stage 128x16 A-tile and W-tile (512 float4 each; 2 per thread)
#pragma unroll
        for (int l = 0; l < 2; ++l) {
            int idx = t + l * 256;
            int rr  = idx >> 2;
            int kk  = (idx & 3) << 2;
            float4 av = *reinterpret_cast<const float4*>(A + (size_t)(rowbase + rr) * DIMC + k0 + kk);
            *reinterpret_cast<float4*>(&As[rr][kk]) = av;   // 80B row stride -> 16B aligned
            float4 wv = *reinterpret_cast<const float4*>(W + (size_t)(colbase + rr) * DIMC + k0 + kk);
            *reinterpret_cast<float4*>(&Ws[rr][kk]) = wv;
        }
        __syncthreads();

#pragma unroll
        for (int kk = 0; kk < BK; kk += 4) {
            float4 a4[8], b4[8];
#pragma unroll
            for (int i = 0; i < 8; ++i) a4[i] = *reinterpret_cast<const float4*>(&As[ty + 16 * i][kk]);
#pragma unroll
            for (int j = 0; j < 8; ++j) b4[j] = *reinterpret_cast<const float4*>(&Ws[tx + 16 * j][kk]);
#pragma unroll
            for (int i = 0; i < 8; ++i) {
#pragma unroll
                for (int j = 0; j < 8; ++j) {
                    acc[i][j] += a4[i].x * b4[j].x + a4[i].y * b4[j].y
                               + a4[i].z * b4[j].z + a4[i].w * b4[j].w;
                }
            }
        }
        __syncthreads();
    }

#pragma unroll
    for (int i = 0; i < 8; ++i) {
        const int r = rowbase + ty + 16 * i;
        float* crow = C + (size_t)r * DIMC + colbase;
#pragma unroll
        for (int j = 0; j < 8; ++j) crow[tx + 16 * j] = acc[i][j];
    }
}

// ---------------------------------------------------------------------------
// Fused RMSNorm + RoPE (+ 1/sqrt(HD) scale folded into Q).
// One wave (64 lanes) per (s, h) row; lane i owns elements (2i, 2i+1).
// ---------------------------------------------------------------------------
__global__ __launch_bounds__(256)
void normrope_kernel(float* __restrict__ Q, float* __restrict__ K,
                     const float* __restrict__ gq,  const float* __restrict__ gk,
                     const float* __restrict__ agq, const float* __restrict__ agk,
                     const float* __restrict__ rc,  const float* __restrict__ rs)
{
    const int wid  = (blockIdx.x * blockDim.x + threadIdx.x) >> 6;
    const int lane = threadIdx.x & 63;
    if (wid >= SEQ * NHEADS) return;
    const int s = wid / NHEADS;
    const int h = wid - s * NHEADS;
    const bool img = (s >= TXTLEN);
    const float* gq_ = img ? gq : agq;
    const float* gk_ = img ? gk : agk;

    const size_t base = (size_t)s * DIMC + h * HD + 2 * lane;
    const float2 c2  = *reinterpret_cast<const float2*>(rc + (size_t)s * HD + 2 * lane);
    const float2 s2  = *reinterpret_cast<const float2*>(rs + (size_t)s * HD + 2 * lane);
    const float2 gqv = *reinterpret_cast<const float2*>(gq_ + 2 * lane);
    const float2 gkv = *reinterpret_cast<const float2*>(gk_ + 2 * lane);

    // Q (scaled by 1/sqrt(128))
    {
        float2 v = *reinterpret_cast<float2*>(Q + base);
        float ss = v.x * v.x + v.y * v.y;
#pragma unroll
        for (int off = 1; off < 64; off <<= 1) ss += __shfl_xor(ss, off);
        const float r = rsqrtf(ss * (1.f / HD) + 1e-6f);
        const float txv = v.x * r * gqv.x, tyv = v.y * r * gqv.y;
        const float qs = 0.08838834764831845f;
        float2 o;
        o.x = (txv * c2.x - tyv * s2.x) * qs;
        o.y = (tyv * c2.y + txv * s2.y) * qs;
        *reinterpret_cast<float2*>(Q + base) = o;
    }
    // K
    {
        float2 v = *reinterpret_cast<float2*>(K + base);
        float ss = v.x * v.x + v.y * v.y;
#pragma unroll
        for (int off = 1; off < 64; off <<= 1) ss += __shfl_xor(ss, off);
        const float r = rsqrtf(ss * (1.f / HD) + 1e-6f);
        const float txv = v.x * r * gkv.x, tyv = v.y * r * gkv.y;
        float2 o;
        o.x = txv * c2.x - tyv * s2.x;
        o.y = tyv * c2.y + txv * s2.y;
        *reinterpret_cast<float2*>(K + base) = o;
    }
}

// ---------------------------------------------------------------------------
// Flash attention (f32): one block per (q-tile of 64, head). 256 threads.
// Scores 64x64 via 4x4 micro-tile; online softmax; P staged in LDS for PV.
// ---------------------------------------------------------------------------
constexpr int QB = 64, KB = 64;
constexpr int QSTRIDE = HD + 4;   // 132 floats (528B rows, 16B aligned)
constexpr int PSTRIDE = KB + 4;   // 68

__global__ __launch_bounds__(256)
void attn_kernel(const float* __restrict__ Q, const float* __restrict__ K,
                 const float* __restrict__ V, float* __restrict__ O)
{
    __shared__ float Qs[QB][QSTRIDE];
    __shared__ float Ks[KB][QSTRIDE];
    __shared__ float Vs[KB][HD];
    __shared__ float Ps[QB][PSTRIDE];

    const int bq = blockIdx.x;
    const int h  = blockIdx.y;
    const int t  = threadIdx.x;
    const int tx = t & 15, ty = t >> 4;

    // load Q tile: 64 rows x 128 cols
#pragma unroll
    for (int l = 0; l < 8; ++l) {
        int idx = t + l * 256;
        int rr  = idx >> 5;
        int dd  = (idx & 31) << 2;
        *reinterpret_cast<float4*>(&Qs[rr][dd]) =
            *reinterpret_cast<const float4*>(Q + (size_t)(bq * QB + rr) * DIMC + h * HD + dd);
    }

    float m[4], lsum[4], o[4][8];
#pragma unroll
    for (int i = 0; i < 4; ++i) { m[i] = -1e30f; lsum[i] = 0.f; }
#pragma unroll
    for (int i = 0; i < 4; ++i)
#pragma unroll
        for (int j = 0; j < 8; ++j) o[i][j] = 0.f;

    for (int kt = 0; kt < SEQ / KB; ++kt) {
        __syncthreads();   // previous PV done before overwriting Ks/Vs
#pragma unroll
        for (int l = 0; l < 8; ++l) {
            int idx = t + l * 256;
            int rr  = idx >> 5;
            int dd  = (idx & 31) << 2;
            *reinterpret_cast<float4*>(&Ks[rr][dd]) =
                *reinterpret_cast<const float4*>(K + (size_t)(kt * KB + rr) * DIMC + h * HD + dd);
            *reinterpret_cast<float4*>(&Vs[rr][dd]) =
                *reinterpret_cast<const float4*>(V + (size_t)(kt * KB + rr) * DIMC + h * HD + dd);
        }
        __syncthreads();

        // scores: 4x4 per thread, rows ty+16i, cols tx+16j
        float sc[4][4];
#pragma unroll
        for (int i = 0; i < 4; ++i)
#pragma unroll
            for (int j = 0; j < 4; ++j) sc[i][j] = 0.f;

        for (int d = 0; d < HD; d += 4) {
            float4 a4[4], b4[4];
#pragma unroll
            for (int i = 0; i < 4; ++i) a4[i] = *reinterpret_cast<const float4*>(&Qs[ty + 16 * i][d]);
#pragma unroll
            for (int j = 0; j < 4; ++j) b4[j] = *reinterpret_cast<const float4*>(&Ks[tx + 16 * j][d]);
#pragma unroll
            for (int i = 0; i < 4; ++i)
#pragma unroll
                for (int j = 0; j < 4; ++j)
                    sc[i][j] += a4[i].x * b4[j].x + a4[i].y * b4[j].y
                              + a4[i].z * b4[j].z + a4[i].w * b4[j].w;
        }

        // online softmax update (row reduce across the 16-lane tx group)
#pragma unroll
        for (int i = 0; i < 4; ++i) {
            float mx = fmaxf(fmaxf(sc[i][0], sc[i][1]), fmaxf(sc[i][2], sc[i][3]));
#pragma unroll
            for (int off = 1; off < 16; off <<= 1) mx = fmaxf(mx, __shfl_xor(mx, off));
            const float mn = fmaxf(m[i], mx);
            const float alpha = __expf(m[i] - mn);
            float psum = 0.f;
#pragma unroll
            for (int j = 0; j < 4; ++j) {
                float p = __expf(sc[i][j] - mn);
                sc[i][j] = p;
                psum += p;
            }
#pragma unroll
            for (int off = 1; off < 16; off <<= 1) psum += __shfl_xor(psum, off);
            lsum[i] = lsum[i] * alpha + psum;
            m[i] = mn;
#pragma unroll
            for (int j = 0; j < 8; ++j) o[i][j] *= alpha;
#pragma unroll
            for (int j = 0; j < 4; ++j) Ps[ty + 16 * i][tx + 16 * j] = sc[i][j];
        }
        // P rows (ty+16i) are written and read by the same 16-lane group of the
        // same wave -> in-order LDS, no barrier needed before PV.

        // PV: o[i][j] += sum_kb P[r][kb] * V[kb][tx+16j]
        for (int kb = 0; kb < KB; kb += 4) {
            float4 pa[4];
#pragma unroll
            for (int i = 0; i < 4; ++i) pa[i] = *reinterpret_cast<const float4*>(&Ps[ty + 16 * i][kb]);
#pragma unroll
            for (int kk = 0; kk < 4; ++kk) {
                float bv[8];
#pragma unroll
                for (int j = 0; j < 8; ++j) bv[j] = Vs[kb + kk][tx + 16 * j];
                const float pc0 = (kk == 0) ? pa[0].x : (kk == 1) ? pa[0].y : (kk == 2) ? pa[0].z : pa[0].w;
                const float pc1 = (kk == 0) ? pa[1].x : (kk == 1) ? pa[1].y : (kk == 2) ? pa[1].z : pa[1].w;
                const float pc2 = (kk == 0) ? pa[2].x : (kk == 1) ? pa[2].y : (kk == 2) ? pa[2].z : pa[2].w;
                const float pc3 = (kk == 0) ? pa[3].x : (kk == 1) ? pa[3].y : (kk == 2) ? pa[3].z : pa[3].w;
#pragma unroll
                for (int j = 0; j < 8; ++j) {
                    o[0][j] += pc0 * bv[j];
                    o[1][j] += pc1 * bv[j];
                    o[2][j] += pc2 * bv[j];
                    o[3][j] += pc3 * bv[j];
                }
            }
        }
    }

    // epilogue: normalize and store
#pragma unroll
    for (int i = 0; i < 4; ++i) {
        const float inv = 1.f / lsum[i];
        float* orow = O + (size_t)(bq * QB + ty + 16 * i) * DIMC + h * HD;
#pragma unroll
        for (int j = 0; j < 8; ++j) orow[tx + 16 * j] = o[i][j] * inv;
    }
}

// ---------------------------------------------------------------------------
extern "C" void kernel_launch(void* const* d_in, const int* in_sizes, int n_in,
                              void* d_out, int out_size, void* d_ws, size_t ws_size,
                              hipStream_t stream)
{
    const float* x    = (const float*)d_in[0];
    const float* ctx  = (const float*)d_in[1];
    const float* rc   = (const float*)d_in[2];
    const float* rs   = (const float*)d_in[3];
    const float* wq   = (const float*)d_in[4];
    const float* wk   = (const float*)d_in[5];
    const float* wv   = (const float*)d_in[6];
    const float* gq   = (const float*)d_in[7];
    const float* gk   = (const float*)d_in[8];
    const float* wo   = (const float*)d_in[9];
    const float* awq  = (const float*)d_in[10];
    const float* awk  = (const float*)d_in[11];
    const float* awv  = (const float*)d_in[12];
    const float* agq  = (const float*)d_in[13];
    const float* agk  = (const float*)d_in[14];
    const float* awo  = (const float*)d_in[15];

    float* out = (float*)d_out;

    const size_t SZ = (size_t)SEQ * DIMC;   // 7,864,320 floats
    float* Qb = (float*)d_ws;
    float* Kb = Qb + SZ;
    float* Vb = Kb + SZ;
    float* Ob = Vb + SZ;

    const dim3 gemm_grid(SEQ / BM, DIMC / BN);
    const dim3 blk(256);

    // QKV projections (txt rows use ctx + aw*, img rows use x + w*)
    gemm_bt_kernel<<<gemm_grid, blk, 0, stream>>>(ctx, x, awq, wq, Qb, Qb + (size_t)TXTLEN * DIMC);
    gemm_bt_kernel<<<gemm_grid, blk, 0, stream>>>(ctx, x, awk, wk, Kb, Kb + (size_t)TXTLEN * DIMC);
    gemm_bt_kernel<<<gemm_grid, blk, 0, stream>>>(ctx, x, awv, wv, Vb, Vb + (size_t)TXTLEN * DIMC);

    // RMSNorm + RoPE (+ q scale)
    normrope_kernel<<<dim3(SEQ * NHEADS / 4), blk, 0, stream>>>(Qb, Kb, gq, gk, agq, agk, rc, rs);

    // attention
    attn_kernel<<<dim3(SEQ / QB, NHEADS), blk, 0, stream>>>(Qb, Kb, Vb, Ob);

    // output projection: img rows -> wo -> d_out[0:], txt rows -> awo -> d_out[IMG*DIM:]
    gemm_bt_kernel<<<gemm_grid, blk, 0, stream>>>(Ob, Ob + (size_t)TXTLEN * DIMC, awo, wo,
                                                  out + (size_t)IMGLEN * DIMC, out);
}

// Round 2
// 601.819 us; speedup vs baseline: 11.3216x; 11.3216x over previous
//
#include <hip/hip_runtime.h>
#include <hip/hip_bf16.h>

#define DIMC 3072
#define NHEADS 24
#define HD 128
#define SEQ 2560
#define TXTLEN 512
#define IMGLEN 2048

using short8 = __attribute__((ext_vector_type(8))) short;
using f32x4  = __attribute__((ext_vector_type(4))) float;

static __device__ __forceinline__ float bf2f(unsigned short u) {
    unsigned v = ((unsigned)u) << 16;
    return __builtin_bit_cast(float, v);
}
static __device__ __forceinline__ unsigned short f2bf(float f) {
    unsigned u = __builtin_bit_cast(unsigned, f);
    return (unsigned short)((u + 0x7FFFu + ((u >> 16) & 1u)) >> 16);
}
static __device__ __forceinline__ void gload16(const void* g, void* l) {
    __builtin_amdgcn_global_load_lds((const __attribute__((address_space(1))) unsigned int*)g,
                                     (__attribute__((address_space(3))) unsigned int*)l,
                                     16, 0, 0);
}

// ---------------------------------------------------------------------------
// f32 -> bf16 cast (vectorized 8/thread)
// ---------------------------------------------------------------------------
__global__ __launch_bounds__(256)
void castk(const float* __restrict__ in, unsigned short* __restrict__ out, int n8)
{
    const int i = blockIdx.x * 256 + threadIdx.x;
    if (i >= n8) return;
    const float4 a = *reinterpret_cast<const float4*>(in + (size_t)i * 8);
    const float4 b = *reinterpret_cast<const float4*>(in + (size_t)i * 8 + 4);
    short8 o;
    o[0] = (short)f2bf(a.x); o[1] = (short)f2bf(a.y);
    o[2] = (short)f2bf(a.z); o[3] = (short)f2bf(a.w);
    o[4] = (short)f2bf(b.x); o[5] = (short)f2bf(b.y);
    o[6] = (short)f2bf(b.z); o[7] = (short)f2bf(b.w);
    *reinterpret_cast<short8*>(out + (size_t)i * 8) = o;
}

// ---------------------------------------------------------------------------
// QKV GEMM (bf16 MFMA, m97 structure): C = A(2560xK) * W(NxK)^T
// grid.y in [0,72): 24 col-blocks per weight {Q,K,V}. Rows<512 use w0 (ctx
// weights), rows>=512 use w1.
// ---------------------------------------------------------------------------
struct QkvArgs {
    const unsigned short* A;
    const unsigned short* w0[3];
    const unsigned short* w1[3];
    unsigned short* c[3];
};

__global__ __launch_bounds__(256)
void gemm_qkv(QkvArgs args)
{
    __shared__ unsigned short As[128 * 32];
    __shared__ unsigned short Bs[128 * 32];

    const int bm = blockIdx.x;
    int bn = blockIdx.y;
    const int which = bn / 24; bn -= which * 24;
    const int rowbase = bm * 128, colbase = bn * 128;
    const unsigned short* __restrict__ A = args.A;
    const unsigned short* __restrict__ W = (rowbase < TXTLEN) ? args.w0[which] : args.w1[which];
    unsigned short* __restrict__ C = args.c[which];

    const int t = threadIdx.x, w = t >> 6, l = t & 63;
    const int lr = l & 15, lk = l >> 4;
    const int wr = (w >> 1) * 64, wc = (w & 1) * 64;

    f32x4 acc[4][4] = {};

    const unsigned short* Ag = A + (size_t)(rowbase + w * 32 + (l >> 2)) * DIMC + (l & 3) * 8;
    const unsigned short* Wg = W + (size_t)(colbase + w * 32 + (l >> 2)) * DIMC + (l & 3) * 8;
    unsigned short* AsB = &As[w * 1024];
    unsigned short* BsB = &Bs[w * 1024];

    for (int k0 = 0; k0 < DIMC; k0 += 32) {
        gload16(Ag + k0,            AsB);
        gload16(Ag + 16 * DIMC + k0, AsB + 512);
        gload16(Wg + k0,            BsB);
        gload16(Wg + 16 * DIMC + k0, BsB + 512);
        __syncthreads();
        short8 af[4], bf[4];
#pragma unroll
        for (int m = 0; m < 4; ++m)
            af[m] = *reinterpret_cast<const short8*>(&As[(wr + m * 16 + lr) * 32 + lk * 8]);
#pragma unroll
        for (int n = 0; n < 4; ++n)
            bf[n] = *reinterpret_cast<const short8*>(&Bs[(wc + n * 16 + lr) * 32 + lk * 8]);
#pragma unroll
        for (int m = 0; m < 4; ++m)
#pragma unroll
            for (int n = 0; n < 4; ++n)
                acc[m][n] = __builtin_amdgcn_mfma_f32_16x16x32_bf16(af[m], bf[n], acc[m][n], 0, 0, 0);
        __syncthreads();
    }

#pragma unroll
    for (int m = 0; m < 4; ++m) {
#pragma unroll
        for (int r = 0; r < 4; ++r) {
            const int row = rowbase + wr + m * 16 + lk * 4 + r;
            unsigned short* crow = C + (size_t)row * DIMC + colbase + wc;
#pragma unroll
            for (int n = 0; n < 4; ++n)
                crow[n * 16 + lr] = f2bf(acc[m][n][r]);
        }
    }
}

// ---------------------------------------------------------------------------
// Output projection GEMM (same core, f32 out, txt/img split)
// ---------------------------------------------------------------------------
__global__ __launch_bounds__(256)
void gemm_out(const unsigned short* __restrict__ A, const unsigned short* __restrict__ W0,
              const unsigned short* __restrict__ W1, float* __restrict__ Ctxt,
              float* __restrict__ Cimg)
{
    __shared__ unsigned short As[128 * 32];
    __shared__ unsigned short Bs[128 * 32];

    const int bm = blockIdx.x, bn = blockIdx.y;
    const int rowbase = bm * 128, colbase = bn * 128;
    const unsigned short* __restrict__ W = (rowbase < TXTLEN) ? W0 : W1;

    const int t = threadIdx.x, w = t >> 6, l = t & 63;
    const int lr = l & 15, lk = l >> 4;
    const int wr = (w >> 1) * 64, wc = (w & 1) * 64;

    f32x4 acc[4][4] = {};

    const unsigned short* Ag = A + (size_t)(rowbase + w * 32 + (l >> 2)) * DIMC + (l & 3) * 8;
    const unsigned short* Wg = W + (size_t)(colbase + w * 32 + (l >> 2)) * DIMC + (l & 3) * 8;
    unsigned short* AsB = &As[w * 1024];
    unsigned short* BsB = &Bs[w * 1024];

    for (int k0 = 0; k0 < DIMC; k0 += 32) {
        gload16(Ag + k0,            AsB);
        gload16(Ag + 16 * DIMC + k0, AsB + 512);
        gload16(Wg + k0,            BsB);
        gload16(Wg + 16 * DIMC + k0, BsB + 512);
        __syncthreads();
        short8 af[4], bf[4];
#pragma unroll
        for (int m = 0; m < 4; ++m)
            af[m] = *reinterpret_cast<const short8*>(&As[(wr + m * 16 + lr) * 32 + lk * 8]);
#pragma unroll
        for (int n = 0; n < 4; ++n)
            bf[n] = *reinterpret_cast<const short8*>(&Bs[(wc + n * 16 + lr) * 32 + lk * 8]);
#pragma unroll
        for (int m = 0; m < 4; ++m)
#pragma unroll
            for (int n = 0; n < 4; ++n)
                acc[m][n] = __builtin_amdgcn_mfma_f32_16x16x32_bf16(af[m], bf[n], acc[m][n], 0, 0, 0);
        __syncthreads();
    }

    float* Cb; int rloc;
    if (rowbase < TXTLEN) { Cb = Ctxt; rloc = rowbase; }
    else                  { Cb = Cimg; rloc = rowbase - TXTLEN; }
#pragma unroll
    for (int m = 0; m < 4; ++m) {
#pragma unroll
        for (int r = 0; r < 4; ++r) {
            const int row = rloc + wr + m * 16 + lk * 4 + r;
            float* crow = Cb + (size_t)row * DIMC + colbase + wc;
#pragma unroll
            for (int n = 0; n < 4; ++n)
                crow[n * 16 + lr] = acc[m][n][r];
        }
    }
}

// ---------------------------------------------------------------------------
// RMSNorm + RoPE (+ 1/sqrt(HD) folded into Q), bf16 in/out.
// One wave per (s,h); lane owns elements (2*lane, 2*lane+1).
// ---------------------------------------------------------------------------
__global__ __launch_bounds__(256)
void normrope(unsigned short* __restrict__ Q, unsigned short* __restrict__ K,
              const float* __restrict__ gq, const float* __restrict__ gk,
              const float* __restrict__ agq, const float* __restrict__ agk,
              const float* __restrict__ rc, const float* __restrict__ rs)
{
    const int wid  = (blockIdx.x << 2) + (threadIdx.x >> 6);
    const int lane = threadIdx.x & 63;
    const int s = wid / NHEADS, h = wid - s * NHEADS;
    const bool img = (s >= TXTLEN);
    const float* gq_ = img ? gq : agq;
    const float* gk_ = img ? gk : agk;

    const size_t base = (size_t)s * DIMC + h * HD + lane * 2;
    const float2 c2  = *reinterpret_cast<const float2*>(rc + (size_t)s * HD + lane * 2);
    const float2 s2  = *reinterpret_cast<const float2*>(rs + (size_t)s * HD + lane * 2);
    const float2 gqv = *reinterpret_cast<const float2*>(gq_ + lane * 2);
    const float2 gkv = *reinterpret_cast<const float2*>(gk_ + lane * 2);

    {
        unsigned pr = *reinterpret_cast<unsigned*>(Q + base);
        float vx = bf2f((unsigned short)(pr & 0xffff));
        float vy = bf2f((unsigned short)(pr >> 16));
        float ss = vx * vx + vy * vy;
#pragma unroll
        for (int off = 1; off < 64; off <<= 1) ss += __shfl_xor(ss, off);
        const float rr = rsqrtf(ss * (1.f / HD) + 1e-6f);
        const float txv = vx * rr * gqv.x, tyv = vy * rr * gqv.y;
        const float qs = 0.08838834764831845f;
        const float ox = (txv * c2.x - tyv * s2.x) * qs;
        const float oy = (tyv * c2.y + txv * s2.y) * qs;
        *reinterpret_cast<unsigned*>(Q + base) = (unsigned)f2bf(ox) | ((unsigned)f2bf(oy) << 16);
    }
    {
        unsigned pr = *reinterpret_cast<unsigned*>(K + base);
        float vx = bf2f((unsigned short)(pr & 0xffff));
        float vy = bf2f((unsigned short)(pr >> 16));
        float ss = vx * vx + vy * vy;
#pragma unroll
        for (int off = 1; off < 64; off <<= 1) ss += __shfl_xor(ss, off);
        const float rr = rsqrtf(ss * (1.f / HD) + 1e-6f);
        const float txv = vx * rr * gkv.x, tyv = vy * rr * gkv.y;
        const float ox = txv * c2.x - tyv * s2.x;
        const float oy = tyv * c2.y + txv * s2.y;
        *reinterpret_cast<unsigned*>(K + base) = (unsigned)f2bf(ox) | ((unsigned)f2bf(oy) << 16);
    }
}

// ---------------------------------------------------------------------------
// V[2560][3072] -> Vt[24][128][2560] (per-head transpose via LDS tile)
// ---------------------------------------------------------------------------
__global__ __launch_bounds__(256)
void transpose_v(const unsigned short* __restrict__ V, unsigned short* __restrict__ Vt)
{
    __shared__ unsigned short Ts[64][136];
    const int kt = blockIdx.x, h = blockIdx.y;
    const int t = threadIdx.x;
#pragma unroll
    for (int p = 0; p < 4; ++p) {
        const int row = p * 16 + (t >> 4);
        const int col = (t & 15) * 8;
        *reinterpret_cast<short8*>(&Ts[row][col]) =
            *reinterpret_cast<const short8*>(V + (size_t)(kt * 64 + row) * DIMC + h * HD + col);
    }
    __syncthreads();
    const int d = t >> 1, kh = t & 1;
    unsigned short* dst = Vt + (size_t)h * HD * SEQ + (size_t)d * SEQ + kt * 64 + kh * 32;
#pragma unroll
    for (int j4 = 0; j4 < 4; ++j4) {
        short8 o;
#pragma unroll
        for (int j = 0; j < 8; ++j) o[j] = (short)Ts[kh * 32 + j4 * 8 + j][d];
        *reinterpret_cast<short8*>(dst + j4 * 8) = o;
    }
}

// ---------------------------------------------------------------------------
// Flash attention, bf16 MFMA. Block = 64 q-rows x 1 head, 4 waves (16 rows
// each). KV tiles of 64. K/Vt staged via global_load_lds with XOR-swizzled
// source (linear LDS dest) + swizzled ds_read (rule #21).
// ---------------------------------------------------------------------------
__global__ __launch_bounds__(256)
void attn_mfma(const unsigned short* __restrict__ Q, const unsigned short* __restrict__ K,
               const unsigned short* __restrict__ Vt, unsigned short* __restrict__ O)
{
    __shared__ unsigned short Ks[64 * 128];   // [kv][d], swizzled: d^((kv&7)<<3)
    __shared__ unsigned short Vs[128 * 64];   // [d][kv], swizzled: kv^((d&7)<<3)
    __shared__ unsigned short Ps[4][16 * 64]; // per-wave [q][kv], swizzled

    const int bq = blockIdx.x, h = blockIdx.y;
    const int t = threadIdx.x, w = t >> 6, l = t & 63;
    const int lr = l & 15, lk = l >> 4;
    const int q0 = bq * 64 + w * 16;

    // Q fragments in registers (Q already scaled by 1/sqrt(HD))
    short8 qf[4];
#pragma unroll
    for (int kk = 0; kk < 4; ++kk)
        qf[kk] = *reinterpret_cast<const short8*>(
            Q + (size_t)(q0 + lr) * DIMC + h * HD + kk * 32 + lk * 8);

    f32x4 oacc[8] = {};
    float mrow[4] = {-1e30f, -1e30f, -1e30f, -1e30f};
    float lrow[4] = {};

    // staging source addresses (pre-swizzled global cols)
    const unsigned short* Kg[4];
    const unsigned short* Vg[4];
#pragma unroll
    for (int c = 0; c < 4; ++c) {
        const int krow = w * 16 + c * 4 + lk;          // kv row within tile
        const int dsl  = lr ^ (krow & 7);              // swizzled 8-elem d slot
        Kg[c] = K + (size_t)krow * DIMC + h * HD + dsl * 8;
        const int vd   = w * 32 + c * 8 + (l >> 3);    // d row
        const int kvsl = (l & 7) ^ (vd & 7);           // swizzled 8-elem kv slot
        Vg[c] = Vt + (size_t)h * HD * SEQ + (size_t)vd * SEQ + kvsl * 8;
    }

    for (int kt = 0; kt < SEQ / 64; ++kt) {
        const int kv0 = kt * 64;
        __syncthreads();
#pragma unroll
        for (int c = 0; c < 4; ++c) {
            gload16(Kg[c] + (size_t)kv0 * DIMC, &Ks[(w * 4 + c) * 512]);
            gload16(Vg[c] + kv0,                &Vs[(w * 4 + c) * 512]);
        }
        __syncthreads();

        // S = Q K^T  (4 col-frags x 4 k-steps)
        f32x4 sf[4] = {};
#pragma unroll
        for (int nf = 0; nf < 4; ++nf) {
            const int row = nf * 16 + lr;
            const int sw = (row & 7) << 3;
#pragma unroll
            for (int kk = 0; kk < 4; ++kk) {
                short8 bfr = *reinterpret_cast<const short8*>(
                    &Ks[row * 128 + ((kk * 32 + lk * 8) ^ sw)]);
                sf[nf] = __builtin_amdgcn_mfma_f32_16x16x32_bf16(qf[kk], bfr, sf[nf], 0, 0, 0);
            }
        }

        // online softmax (rows lk*4+r; reduce across the 16-lane lr group)
        float alpha[4];
#pragma unroll
        for (int r = 0; r < 4; ++r) {
            float mx = fmaxf(fmaxf(sf[0][r], sf[1][r]), fmaxf(sf[2][r], sf[3][r]));
#pragma unroll
            for (int off = 1; off < 16; off <<= 1) mx = fmaxf(mx, __shfl_xor(mx, off));
            const float mn = fmaxf(mrow[r], mx);
            alpha[r] = __expf(mrow[r] - mn);
            mrow[r] = mn;
            float ps = 0.f;
#pragma unroll
            for (int nf = 0; nf < 4; ++nf) {
                const float p = __expf(sf[nf][r] - mn);
                sf[nf][r] = p;
                ps += p;
            }
#pragma unroll
            for (int off = 1; off < 16; off <<= 1) ps += __shfl_xor(ps, off);
            lrow[r] = lrow[r] * alpha[r] + ps;
        }
#pragma unroll
        for (int nf = 0; nf < 8; ++nf)
#pragma unroll
            for (int r = 0; r < 4; ++r) oacc[nf][r] *= alpha[r];

        // P -> per-wave LDS (bf16, swizzled); same-wave producer/consumer
#pragma unroll
        for (int r = 0; r < 4; ++r) {
            const int prow = lk * 4 + r;
            const int sw = (prow & 7) << 3;
#pragma unroll
            for (int nf = 0; nf < 4; ++nf) {
                const int col = nf * 16 + lr;
                Ps[w][prow * 64 + (col ^ sw)] = f2bf(sf[nf][r]);
            }
        }

        // O += P V
#pragma unroll
        for (int ks = 0; ks < 2; ++ks) {
            short8 pa = *reinterpret_cast<const short8*>(
                &Ps[w][lr * 64 + ((ks * 32 + lk * 8) ^ ((lr & 7) << 3))]);
#pragma unroll
            for (int nf = 0; nf < 8; ++nf) {
                const int vrow = nf * 16 + lr;
                short8 vf = *reinterpret_cast<const short8*>(
                    &Vs[vrow * 64 + ((ks * 32 + lk * 8) ^ ((vrow & 7) << 3))]);
                oacc[nf] = __builtin_amdgcn_mfma_f32_16x16x32_bf16(pa, vf, oacc[nf], 0, 0, 0);
            }
        }
    }

    float inv[4];
#pragma unroll
    for (int r = 0; r < 4; ++r) inv[r] = 1.f / lrow[r];
#pragma unroll
    for (int nf = 0; nf < 8; ++nf)
#pragma unroll
        for (int r = 0; r < 4; ++r)
            O[(size_t)(q0 + lk * 4 + r) * DIMC + h * HD + nf * 16 + lr] = f2bf(oacc[nf][r] * inv[r]);
}

// ---------------------------------------------------------------------------
extern "C" void kernel_launch(void* const* d_in, const int* in_sizes, int n_in,
                              void* d_out, int out_size, void* d_ws, size_t ws_size,
                              hipStream_t stream)
{
    const float* x    = (const float*)d_in[0];
    const float* ctx  = (const float*)d_in[1];
    const float* rc   = (const float*)d_in[2];
    const float* rs   = (const float*)d_in[3];
    const float* wq   = (const float*)d_in[4];
    const float* wk   = (const float*)d_in[5];
    const float* wv   = (const float*)d_in[6];
    const float* gq   = (const float*)d_in[7];
    const float* gk   = (const float*)d_in[8];
    const float* wo   = (const float*)d_in[9];
    const float* awq  = (const float*)d_in[10];
    const float* awk  = (const float*)d_in[11];
    const float* awv  = (const float*)d_in[12];
    const float* agq  = (const float*)d_in[13];
    const float* agk  = (const float*)d_in[14];
    const float* awo  = (const float*)d_in[15];

    unsigned short* wsp = (unsigned short*)d_ws;
    const size_t SZ  = (size_t)SEQ * DIMC;
    const size_t WSZ = (size_t)DIMC * DIMC;
    unsigned short* XC  = wsp;
    unsigned short* Qb  = XC + SZ;
    unsigned short* Kb  = Qb + SZ;
    unsigned short* Vb  = Kb + SZ;
    unsigned short* Vtb = Vb + SZ;
    unsigned short* Ob  = Vtb + SZ;
    unsigned short* Wc[8];  // awq, wq, awk, wk, awv, wv, awo, wo
    for (int i = 0; i < 8; ++i) Wc[i] = Ob + SZ + (size_t)i * WSZ;

    auto cast = [&](const float* src, unsigned short* dst, size_t n) {
        const int n8 = (int)(n / 8);
        castk<<<dim3((n8 + 255) / 256), dim3(256), 0, stream>>>(src, dst, n8);
    };
    cast(ctx, XC, (size_t)TXTLEN * DIMC);
    cast(x,   XC + (size_t)TXTLEN * DIMC, (size_t)IMGLEN * DIMC);
    cast(awq, Wc[0], WSZ); cast(wq, Wc[1], WSZ);
    cast(awk, Wc[2], WSZ); cast(wk, Wc[3], WSZ);
    cast(awv, Wc[4], WSZ); cast(wv, Wc[5], WSZ);
    cast(awo, Wc[6], WSZ); cast(wo, Wc[7], WSZ);

    QkvArgs qa;
    qa.A = XC;
    qa.w0[0] = Wc[0]; qa.w1[0] = Wc[1]; qa.c[0] = Qb;
    qa.w0[1] = Wc[2]; qa.w1[1] = Wc[3]; qa.c[1] = Kb;
    qa.w0[2] = Wc[4]; qa.w1[2] = Wc[5]; qa.c[2] = Vb;
    gemm_qkv<<<dim3(SEQ / 128, 72), dim3(256), 0, stream>>>(qa);

    normrope<<<dim3(SEQ * NHEADS / 4), dim3(256), 0, stream>>>(Qb, Kb, gq, gk, agq, agk, rc, rs);

    transpose_v<<<dim3(SEQ / 64, NHEADS), dim3(256), 0, stream>>>(Vb, Vtb);

    attn_mfma<<<dim3(SEQ / 64, NHEADS), dim3(256), 0, stream>>>(Qb, Kb, Vtb, Ob);

    float* out = (float*)d_out;
    gemm_out<<<dim3(SEQ / 128, DIMC / 128), dim3(256), 0, stream>>>(
        Ob, Wc[6], Wc[7], out + (size_t)IMGLEN * DIMC, out);
}